// Round 13
// baseline (263.452 us; speedup 1.0000x reference)
//
#include <hip/hip_runtime.h>
#include <hip/hip_bf16.h>
#include <hip/hip_fp16.h>

// GCN: h1 = relu(GCNConv(x,W1,b1)); h2 = GCNConv(h1,W2,b2);
//      h3 = relu(h2@Wm1+bm1); out = h3@Wm2+bm2
// R2: CSR-by-dst gather-reduce replaced scatter atomics (10x write amp).
// R4: 2-pass XCD-local bucket sort (fill_kernel had 8x write amp).
// R5: dinv folded into GEMM epilogue (g = h*dinv); padded rows, sentinel col.
// R6/R8 FAILED: multi-phase LDS GEMM fusion -> 256 VGPR scratch spills.
// R7: fp16 g-tables (gather path only). R9: 2-node/wave aggregate (255.8us).
// R10/R11 FAILED: fp16 intermediates (issue-bound GEMMs gain cvt chains).
// R12 NEUTRAL: 256-node buckets (260us). R9 config restored.
// R13: (a) CSR rows padded to 4 not 8 + 4-wide aggregate unroll: ~24% fewer
//      gather instrs (E[maxpair trips]x4 = 12.8 vs 16.8); occupancy covers
//      the halved ILP. (b) zero_detect kernel deleted: bucketCnt via
//      hipMemsetAsync, int32/int64 detection in-block in bucket_kernel.

namespace {

constexpr int N_NODES = 100000;
constexpr int N_EDGES = 1000000;
constexpr int NBUCK = (N_NODES + 511) / 512;  // 196 buckets of 512 nodes
constexpr int CAP = 8192;      // bucket capacity (pad4 mean ~6077, sd ~75)
constexpr int EPB_A = 2048;    // edges per passA block

// passA: partition edges into NBUCK buckets by dst>>9. word=(src<<9)|(dst&511).
// Per-block int32/int64 detection: sample 512 odd words of own range (int64
// high halves are all 0; int32 node ids ~surely not).
__global__ __launch_bounds__(256) void bucket_kernel(const void* __restrict__ ei,
                                                     int* __restrict__ bucketCnt,
                                                     unsigned* __restrict__ tmp) {
  __shared__ int hist[NBUCK];
  __shared__ int basePB[NBUCK];
  __shared__ int cur[NBUCK];
  __shared__ int sflag;
  int t = threadIdx.x;
  if (t < NBUCK) { hist[t] = 0; cur[t] = 0; }
  if (t == 0) sflag = 0;
  __syncthreads();

  int e0 = blockIdx.x * EPB_A;
  const unsigned* w = (const unsigned*)ei;
  unsigned any = 0;
#pragma unroll
  for (int s = 0; s < 2; s++) {
    int e = e0 + s * 256 + t;
    if (e < N_EDGES) any |= w[2 * e + 1];
  }
  if (any) sflag = 1;  // benign race, all writers store 1
  __syncthreads();
  int is32 = sflag;

  unsigned wreg[8];
  int breg[8];
#pragma unroll
  for (int k = 0; k < 8; k++) {
    int e = e0 + k * 256 + t;
    breg[k] = -1;
    if (e < N_EDGES) {
      int s, d;
      if (is32) {
        const int* p = (const int*)ei;
        s = p[e]; d = p[N_EDGES + e];
      } else {
        const long long* p = (const long long*)ei;
        s = (int)p[e]; d = (int)p[N_EDGES + e];
      }
      wreg[k] = ((unsigned)s << 9) | (unsigned)(d & 511);
      breg[k] = d >> 9;
      atomicAdd(&hist[breg[k]], 1);
    }
  }
  __syncthreads();
  if (t < NBUCK) basePB[t] = hist[t] ? atomicAdd(&bucketCnt[t], hist[t]) : 0;
  __syncthreads();
#pragma unroll
  for (int k = 0; k < 8; k++) {
    if (breg[k] >= 0) {
      int r = atomicAdd(&cur[breg[k]], 1);
      tmp[(size_t)breg[k] * CAP + basePB[breg[k]] + r] = wreg[k];
    }
  }
}

// passB: one block per bucket. LDS counting sort; rows padded to mult 4 with
// sentinel N_NODES (zero row); emit row_start/row_end + dinv.
__global__ __launch_bounds__(512) void csr_kernel(const unsigned* __restrict__ tmp,
                                                  const int* __restrict__ bucketCnt,
                                                  int* __restrict__ col,
                                                  int* __restrict__ row_start,
                                                  int* __restrict__ row_end,
                                                  float* __restrict__ dinv) {
  __shared__ int sc[512];
  __shared__ int hist[512];
  __shared__ unsigned stage[CAP];
  int b = blockIdx.x, t = threadIdx.x;
  int myCnt = bucketCnt[b];
  int base = b * CAP;

  hist[t] = 0;
  __syncthreads();
  for (int i = t; i < myCnt; i += 512) {
    unsigned w = tmp[(size_t)base + i];
    stage[i] = w;
    atomicAdd(&hist[w & 511u], 1);
  }
  __syncthreads();

  int deg = hist[t];
  int pdeg = (deg + 3) & ~3;  // pad rows to mult 4 (16B-aligned col segments)
  sc[t] = pdeg;
  __syncthreads();
#pragma unroll
  for (int off = 1; off < 512; off <<= 1) {
    int u = (t >= off) ? sc[t - off] : 0;
    __syncthreads();
    sc[t] += u;
    __syncthreads();
  }
  int pexcl = sc[t] - pdeg;
  int d = b * 512 + t;
  if (d < N_NODES) {
    row_start[d] = base + pexcl;
    row_end[d] = base + pexcl + pdeg;
    dinv[d] = rsqrtf((float)deg + 1.0f);
  }
  __syncthreads();
  hist[t] = pexcl;
  __syncthreads();
  for (int i = t; i < myCnt; i += 512) {
    unsigned w = stage[i];
    int pos = atomicAdd(&hist[w & 511u], 1);
    col[base + pos] = (int)(w >> 9);
  }
  for (int j = deg; j < pdeg; j++) col[base + pexcl + j] = N_NODES;
}

__device__ inline uint4 pack_half8(const float* v) {
  __half2 h0 = __floats2half2_rn(v[0], v[1]);
  __half2 h1 = __floats2half2_rn(v[2], v[3]);
  __half2 h2 = __floats2half2_rn(v[4], v[5]);
  __half2 h3 = __floats2half2_rn(v[6], v[7]);
  uint4 u;
  u.x = *(unsigned*)&h0; u.y = *(unsigned*)&h1;
  u.z = *(unsigned*)&h2; u.w = *(unsigned*)&h3;
  return u;
}

// g[r] = (op(A[r])@W) * dinv[r], fp16 out, zero pad row N_NODES.
// 128 rows/block, 256 thr, thread = 4 rows x 8 cols. W staged in LDS.
__global__ __launch_bounds__(256) void gemm_g_kernel(const float* __restrict__ A,
                                                     const float* __restrict__ W,
                                                     const float* __restrict__ dinv,
                                                     __half* __restrict__ g,
                                                     int reluIn) {
  __shared__ float Ws[64 * 64];
  int t = threadIdx.x;
  if (blockIdx.x == 0 && t < 32) ((float*)(g + (size_t)N_NODES * 64))[t] = 0.f;  // pad row
  for (int i = t; i < 64 * 64 / 4; i += 256) ((float4*)Ws)[i] = ((const float4*)W)[i];
  __syncthreads();

  int rg = t >> 3, cg = t & 7;
  int r0 = blockIdx.x * 128 + rg * 4;
  int c0 = cg * 8;

  float acc[4][8];
#pragma unroll
  for (int i = 0; i < 4; i++)
#pragma unroll
    for (int j = 0; j < 8; j++) acc[i][j] = 0.f;

  const float4* A4 = (const float4*)A;
  for (int kk = 0; kk < 16; kk++) {
    float4 a[4];
#pragma unroll
    for (int i = 0; i < 4; i++) {
      int r = r0 + i;
      float4 v = (r < N_NODES) ? A4[(size_t)r * 16 + kk] : make_float4(0.f, 0.f, 0.f, 0.f);
      if (reluIn) {
        v.x = fmaxf(v.x, 0.f); v.y = fmaxf(v.y, 0.f);
        v.z = fmaxf(v.z, 0.f); v.w = fmaxf(v.w, 0.f);
      }
      a[i] = v;
    }
#pragma unroll
    for (int q = 0; q < 4; q++) {
      int k = kk * 4 + q;
      float w[8];
#pragma unroll
      for (int j = 0; j < 2; j++) *(float4*)&w[4 * j] = *(const float4*)&Ws[k * 64 + c0 + 4 * j];
#pragma unroll
      for (int i = 0; i < 4; i++) {
        float av = q == 0 ? a[i].x : q == 1 ? a[i].y : q == 2 ? a[i].z : a[i].w;
#pragma unroll
        for (int j = 0; j < 8; j++) acc[i][j] = fmaf(av, w[j], acc[i][j]);
      }
    }
  }
#pragma unroll
  for (int i = 0; i < 4; i++) {
    int r = r0 + i;
    if (r < N_NODES) {
      float s = dinv[r];
#pragma unroll
      for (int j = 0; j < 8; j++) acc[i][j] *= s;
      *(uint4*)(g + (size_t)r * 64 + c0) = pack_half8(acc[i]);
    }
  }
}

// Per-node gather-reduce, 2 nodes per wave: lanes 0-31 node d0, lanes 32-63
// node d1; each lane covers 2 features as one half2 -> one gather instr
// fetches TWO 128B rows. Rows padded to mult 4 (pad cols hit zero row):
// one int4 col broadcast + 4 gathers + 4 adds per iter, no predication.
// fp32 accum/out. grid*8 == N_NODES exactly (12500 blocks).
__global__ __launch_bounds__(256) void aggregate_kernel(const __half* __restrict__ g,
                                                        const int* __restrict__ col,
                                                        const int* __restrict__ row_start,
                                                        const int* __restrict__ row_end,
                                                        const float* __restrict__ dinv,
                                                        const float* __restrict__ bias,
                                                        float* __restrict__ out) {
  int wave = threadIdx.x >> 6;
  int lane = threadIdx.x & 63;
  int half = lane >> 5;
  int sub = lane & 31;
  int d = blockIdx.x * 8 + wave * 2 + half;

  const __half2* g2 = (const __half2*)g;
  int e0 = row_start[d];
  int len = row_end[d] - e0;

  float2 a0 = __half22float2(g2[(size_t)d * 32 + sub]);  // self (dinv in g)
  float2 a1 = {0.f, 0.f}, a2 = {0.f, 0.f}, a3 = {0.f, 0.f};

  for (int i = 0; i < len; i += 4) {  // per-half-wave trip count (exec-mask divergence)
    int4 ca = *(const int4*)(col + e0 + i);  // broadcast, 16B aligned
    float2 h0 = __half22float2(g2[(size_t)ca.x * 32 + sub]);
    float2 h1 = __half22float2(g2[(size_t)ca.y * 32 + sub]);
    float2 h2 = __half22float2(g2[(size_t)ca.z * 32 + sub]);
    float2 h3 = __half22float2(g2[(size_t)ca.w * 32 + sub]);
    a0.x += h0.x; a0.y += h0.y; a1.x += h1.x; a1.y += h1.y;
    a2.x += h2.x; a2.y += h2.y; a3.x += h3.x; a3.y += h3.y;
  }
  float rx = (a0.x + a1.x) + (a2.x + a3.x);
  float ry = (a0.y + a1.y) + (a2.y + a3.y);
  float dv = dinv[d];
  float2 bv = ((const float2*)bias)[sub];
  float2 o;
  o.x = fmaf(rx, dv, bv.x);
  o.y = fmaf(ry, dv, bv.y);
  ((float2*)out)[(size_t)d * 32 + sub] = o;
}

// fp32 GEMM for the MLP: C[n,F] = op(A[n,64])@W[64,F] (+bias)(relu).
// Single-phase only (see R6/R8 spill rule).
template <int F>
__global__ __launch_bounds__(256) void gemm_kernel(const float* __restrict__ A, const float* __restrict__ W,
                                                   const float* __restrict__ bias, float* __restrict__ C,
                                                   int n, int reluIn, int reluOut) {
  constexpr int CPT = F / 8;
  __shared__ float Ws[64 * F];
  int t = threadIdx.x;
  for (int i = t; i < 64 * F / 4; i += 256) ((float4*)Ws)[i] = ((const float4*)W)[i];
  __syncthreads();

  int rg = t >> 3, cg = t & 7;
  int r0 = blockIdx.x * 128 + rg * 4;
  int c0 = cg * CPT;

  float acc[4][CPT];
#pragma unroll
  for (int i = 0; i < 4; i++)
#pragma unroll
    for (int j = 0; j < CPT; j++) acc[i][j] = 0.f;

  const float4* A4 = (const float4*)A;
  for (int kk = 0; kk < 16; kk++) {
    float4 a[4];
#pragma unroll
    for (int i = 0; i < 4; i++) {
      int r = r0 + i;
      float4 v = (r < n) ? A4[(size_t)r * 16 + kk] : make_float4(0.f, 0.f, 0.f, 0.f);
      if (reluIn) {
        v.x = fmaxf(v.x, 0.f); v.y = fmaxf(v.y, 0.f);
        v.z = fmaxf(v.z, 0.f); v.w = fmaxf(v.w, 0.f);
      }
      a[i] = v;
    }
#pragma unroll
    for (int q = 0; q < 4; q++) {
      int k = kk * 4 + q;
      float w[CPT];
      if constexpr (CPT % 4 == 0) {
#pragma unroll
        for (int j = 0; j < CPT / 4; j++)
          *(float4*)&w[4 * j] = *(const float4*)&Ws[k * F + c0 + 4 * j];  // ds_read_b128
      } else {
#pragma unroll
        for (int j = 0; j < CPT; j++) w[j] = Ws[k * F + c0 + j];
      }
#pragma unroll
      for (int i = 0; i < 4; i++) {
        float av = q == 0 ? a[i].x : q == 1 ? a[i].y : q == 2 ? a[i].z : a[i].w;
#pragma unroll
        for (int j = 0; j < CPT; j++) acc[i][j] = fmaf(av, w[j], acc[i][j]);
      }
    }
  }

  float bv[CPT];
#pragma unroll
  for (int j = 0; j < CPT; j++) bv[j] = bias ? bias[c0 + j] : 0.f;
#pragma unroll
  for (int i = 0; i < 4; i++) {
    int r = r0 + i;
    if (r < n) {
      float* crow = C + (size_t)r * F + c0;
#pragma unroll
      for (int j = 0; j < CPT; j++) {
        float v = acc[i][j] + bv[j];
        if (reluOut) v = fmaxf(v, 0.f);
        crow[j] = v;
      }
    }
  }
}

}  // namespace

extern "C" void kernel_launch(void* const* d_in, const int* in_sizes, int n_in,
                              void* d_out, int out_size, void* d_ws, size_t ws_size,
                              hipStream_t stream) {
  const float* x   = (const float*)d_in[0];
  const void*  ei  = d_in[1];
  const float* W1  = (const float*)d_in[2];
  const float* b1  = (const float*)d_in[3];
  const float* W2  = (const float*)d_in[4];
  const float* b2  = (const float*)d_in[5];
  const float* Wm1 = (const float*)d_in[6];
  const float* bm1 = (const float*)d_in[7];
  const float* Wm2 = (const float*)d_in[8];
  const float* bm2 = (const float*)d_in[9];
  float* out = (float*)d_out;

  char* ws = (char*)d_ws;
  size_t off = 0;
  auto alloc = [&](size_t bytes) -> void* {
    void* p = ws + off;
    off = (off + bytes + 511) & ~(size_t)511;
    return p;
  };
  int*      bucketCnt = (int*)     alloc((size_t)NBUCK * 4);
  unsigned* tmp       = (unsigned*)alloc((size_t)NBUCK * CAP * 4);  // 6.4 MB
  int*      colA      = (int*)     alloc((size_t)NBUCK * CAP * 4);  // 6.4 MB
  int*      rowS      = (int*)     alloc((size_t)N_NODES * 4);
  int*      rowE      = (int*)     alloc((size_t)N_NODES * 4);
  float*    dinv      = (float*)   alloc((size_t)N_NODES * 4);
  __half*   g1        = (__half*)  alloc((size_t)(N_NODES + 1) * 64 * 2);  // +1 zero row
  float*    hA        = (float*)   alloc((size_t)N_NODES * 64 * 4);
  float*    hB        = (float*)   alloc((size_t)N_NODES * 64 * 4);
  (void)ws_size; (void)in_sizes; (void)n_in; (void)out_size;

  dim3 b256(256);
  int gGemm = (N_NODES + 127) / 128;
  int gAgg  = N_NODES / 8;  // 12500, exact
  int gBkt  = (N_EDGES + EPB_A - 1) / EPB_A;

  // preprocessing: 2-pass bucket sort -> padded CSR (shared by both convs)
  hipMemsetAsync(bucketCnt, 0, (size_t)NBUCK * 4, stream);
  bucket_kernel<<<gBkt, b256, 0, stream>>>(ei, bucketCnt, tmp);
  csr_kernel<<<NBUCK, dim3(512), 0, stream>>>(tmp, bucketCnt, colA, rowS, rowE, dinv);

  // conv1: g1 = (x@W1)*dinv (fp16); hB = dinv*(self+SUM)+b1 (fp32)
  gemm_g_kernel<<<gGemm, b256, 0, stream>>>(x, W1, dinv, g1, 0);
  aggregate_kernel<<<gAgg, b256, 0, stream>>>(g1, colA, rowS, rowE, dinv, b1, hB);

  // conv2: g1 = (relu(hB)@W2)*dinv (fp16); hB = dinv*(self+SUM)+b2 (fp32)
  gemm_g_kernel<<<gGemm, b256, 0, stream>>>(hB, W2, dinv, g1, 1);
  aggregate_kernel<<<gAgg, b256, 0, stream>>>(g1, colA, rowS, rowE, dinv, b2, hB);

  // MLP: hA = relu(hB@Wm1+bm1); out = hA@Wm2+bm2  (two single-phase GEMMs)
  gemm_kernel<64><<<gGemm, b256, 0, stream>>>(hB, Wm1, bm1, hA, N_NODES, 0, 1);
  gemm_kernel<40><<<gGemm, b256, 0, stream>>>(hA, Wm2, bm2, out, N_NODES, 0, 0);
}

// Round 14
// 253.342 us; speedup vs baseline: 1.0399x; 1.0399x over previous
//
#include <hip/hip_runtime.h>
#include <hip/hip_bf16.h>
#include <hip/hip_fp16.h>

// GCN: h1 = relu(GCNConv(x,W1,b1)); h2 = GCNConv(h1,W2,b2);
//      h3 = relu(h2@Wm1+bm1); out = h3@Wm2+bm2
// R2: CSR-by-dst gather-reduce replaced scatter atomics (10x write amp).
// R4: 2-pass XCD-local bucket sort (fill_kernel had 8x write amp).
// R5: dinv folded into GEMM epilogue (g = h*dinv); padded rows, sentinel col.
// R6/R8 FAILED: multi-phase LDS GEMM fusion -> 256 VGPR scratch spills.
// R7: fp16 g-tables (gather path only). R9: 2-node/wave aggregate (255.8us).
// R10/R11 FAILED: fp16 intermediates. R12 NEUTRAL: 256-node buckets.
// R13 FAILED: pad-4/4-wide aggregate (263us) -- latency-bound kernel needs
//      the 8-deep gather pipeline; instruction count is secondary.
// R14: exact R9 aggregate (pad-8, 8-wide) + R13's preprocessing cleanup only
//      (bucketCnt via hipMemsetAsync; dtype detection in-block in passA).

namespace {

constexpr int N_NODES = 100000;
constexpr int N_EDGES = 1000000;
constexpr int NBUCK = (N_NODES + 511) / 512;  // 196 buckets of 512 nodes
constexpr int CAP = 8192;      // bucket capacity (pad8 mean ~6963, sd ~88)
constexpr int EPB_A = 2048;    // edges per passA block

// passA: partition edges into NBUCK buckets by dst>>9. word=(src<<9)|(dst&511).
// Per-block int32/int64 detection: sample 512 odd words of own range (int64
// high halves are all 0; int32 node ids ~surely not).
__global__ __launch_bounds__(256) void bucket_kernel(const void* __restrict__ ei,
                                                     int* __restrict__ bucketCnt,
                                                     unsigned* __restrict__ tmp) {
  __shared__ int hist[NBUCK];
  __shared__ int basePB[NBUCK];
  __shared__ int cur[NBUCK];
  __shared__ int sflag;
  int t = threadIdx.x;
  if (t < NBUCK) { hist[t] = 0; cur[t] = 0; }
  if (t == 0) sflag = 0;
  __syncthreads();

  int e0 = blockIdx.x * EPB_A;
  const unsigned* w = (const unsigned*)ei;
  unsigned any = 0;
#pragma unroll
  for (int s = 0; s < 2; s++) {
    int e = e0 + s * 256 + t;
    if (e < N_EDGES) any |= w[2 * e + 1];
  }
  if (any) sflag = 1;  // benign race, all writers store 1
  __syncthreads();
  int is32 = sflag;

  unsigned wreg[8];
  int breg[8];
#pragma unroll
  for (int k = 0; k < 8; k++) {
    int e = e0 + k * 256 + t;
    breg[k] = -1;
    if (e < N_EDGES) {
      int s, d;
      if (is32) {
        const int* p = (const int*)ei;
        s = p[e]; d = p[N_EDGES + e];
      } else {
        const long long* p = (const long long*)ei;
        s = (int)p[e]; d = (int)p[N_EDGES + e];
      }
      wreg[k] = ((unsigned)s << 9) | (unsigned)(d & 511);
      breg[k] = d >> 9;
      atomicAdd(&hist[breg[k]], 1);
    }
  }
  __syncthreads();
  if (t < NBUCK) basePB[t] = hist[t] ? atomicAdd(&bucketCnt[t], hist[t]) : 0;
  __syncthreads();
#pragma unroll
  for (int k = 0; k < 8; k++) {
    if (breg[k] >= 0) {
      int r = atomicAdd(&cur[breg[k]], 1);
      tmp[(size_t)breg[k] * CAP + basePB[breg[k]] + r] = wreg[k];
    }
  }
}

// passB: one block per bucket. LDS counting sort; rows padded to mult 8 with
// sentinel N_NODES (zero row); emit row_start/row_end + dinv.
__global__ __launch_bounds__(512) void csr_kernel(const unsigned* __restrict__ tmp,
                                                  const int* __restrict__ bucketCnt,
                                                  int* __restrict__ col,
                                                  int* __restrict__ row_start,
                                                  int* __restrict__ row_end,
                                                  float* __restrict__ dinv) {
  __shared__ int sc[512];
  __shared__ int hist[512];
  __shared__ unsigned stage[CAP];
  int b = blockIdx.x, t = threadIdx.x;
  int myCnt = bucketCnt[b];
  int base = b * CAP;

  hist[t] = 0;
  __syncthreads();
  for (int i = t; i < myCnt; i += 512) {
    unsigned w = tmp[(size_t)base + i];
    stage[i] = w;
    atomicAdd(&hist[w & 511u], 1);
  }
  __syncthreads();

  int deg = hist[t];
  int pdeg = (deg + 7) & ~7;  // pad rows to mult 8 (R9-proven 8-deep pipeline)
  sc[t] = pdeg;
  __syncthreads();
#pragma unroll
  for (int off = 1; off < 512; off <<= 1) {
    int u = (t >= off) ? sc[t - off] : 0;
    __syncthreads();
    sc[t] += u;
    __syncthreads();
  }
  int pexcl = sc[t] - pdeg;
  int d = b * 512 + t;
  if (d < N_NODES) {
    row_start[d] = base + pexcl;
    row_end[d] = base + pexcl + pdeg;
    dinv[d] = rsqrtf((float)deg + 1.0f);
  }
  __syncthreads();
  hist[t] = pexcl;
  __syncthreads();
  for (int i = t; i < myCnt; i += 512) {
    unsigned w = stage[i];
    int pos = atomicAdd(&hist[w & 511u], 1);
    col[base + pos] = (int)(w >> 9);
  }
  for (int j = deg; j < pdeg; j++) col[base + pexcl + j] = N_NODES;
}

__device__ inline uint4 pack_half8(const float* v) {
  __half2 h0 = __floats2half2_rn(v[0], v[1]);
  __half2 h1 = __floats2half2_rn(v[2], v[3]);
  __half2 h2 = __floats2half2_rn(v[4], v[5]);
  __half2 h3 = __floats2half2_rn(v[6], v[7]);
  uint4 u;
  u.x = *(unsigned*)&h0; u.y = *(unsigned*)&h1;
  u.z = *(unsigned*)&h2; u.w = *(unsigned*)&h3;
  return u;
}

// g[r] = (op(A[r])@W) * dinv[r], fp16 out, zero pad row N_NODES.
// 128 rows/block, 256 thr, thread = 4 rows x 8 cols. W staged in LDS.
__global__ __launch_bounds__(256) void gemm_g_kernel(const float* __restrict__ A,
                                                     const float* __restrict__ W,
                                                     const float* __restrict__ dinv,
                                                     __half* __restrict__ g,
                                                     int reluIn) {
  __shared__ float Ws[64 * 64];
  int t = threadIdx.x;
  if (blockIdx.x == 0 && t < 32) ((float*)(g + (size_t)N_NODES * 64))[t] = 0.f;  // pad row
  for (int i = t; i < 64 * 64 / 4; i += 256) ((float4*)Ws)[i] = ((const float4*)W)[i];
  __syncthreads();

  int rg = t >> 3, cg = t & 7;
  int r0 = blockIdx.x * 128 + rg * 4;
  int c0 = cg * 8;

  float acc[4][8];
#pragma unroll
  for (int i = 0; i < 4; i++)
#pragma unroll
    for (int j = 0; j < 8; j++) acc[i][j] = 0.f;

  const float4* A4 = (const float4*)A;
  for (int kk = 0; kk < 16; kk++) {
    float4 a[4];
#pragma unroll
    for (int i = 0; i < 4; i++) {
      int r = r0 + i;
      float4 v = (r < N_NODES) ? A4[(size_t)r * 16 + kk] : make_float4(0.f, 0.f, 0.f, 0.f);
      if (reluIn) {
        v.x = fmaxf(v.x, 0.f); v.y = fmaxf(v.y, 0.f);
        v.z = fmaxf(v.z, 0.f); v.w = fmaxf(v.w, 0.f);
      }
      a[i] = v;
    }
#pragma unroll
    for (int q = 0; q < 4; q++) {
      int k = kk * 4 + q;
      float w[8];
#pragma unroll
      for (int j = 0; j < 2; j++) *(float4*)&w[4 * j] = *(const float4*)&Ws[k * 64 + c0 + 4 * j];
#pragma unroll
      for (int i = 0; i < 4; i++) {
        float av = q == 0 ? a[i].x : q == 1 ? a[i].y : q == 2 ? a[i].z : a[i].w;
#pragma unroll
        for (int j = 0; j < 8; j++) acc[i][j] = fmaf(av, w[j], acc[i][j]);
      }
    }
  }
#pragma unroll
  for (int i = 0; i < 4; i++) {
    int r = r0 + i;
    if (r < N_NODES) {
      float s = dinv[r];
#pragma unroll
      for (int j = 0; j < 8; j++) acc[i][j] *= s;
      *(uint4*)(g + (size_t)r * 64 + c0) = pack_half8(acc[i]);
    }
  }
}

// Per-node gather-reduce, 2 nodes per wave (R9-proven): lanes 0-31 node d0,
// lanes 32-63 node d1; each lane covers 2 features as one half2 -> one
// gather instr fetches TWO 128B rows; 8-deep gather pipeline. Half-wave
// edge loops diverge on exec mask. fp32 accum/out. grid*8 == N_NODES.
__global__ __launch_bounds__(256) void aggregate_kernel(const __half* __restrict__ g,
                                                        const int* __restrict__ col,
                                                        const int* __restrict__ row_start,
                                                        const int* __restrict__ row_end,
                                                        const float* __restrict__ dinv,
                                                        const float* __restrict__ bias,
                                                        float* __restrict__ out) {
  int wave = threadIdx.x >> 6;
  int lane = threadIdx.x & 63;
  int half = lane >> 5;
  int sub = lane & 31;
  int d = blockIdx.x * 8 + wave * 2 + half;

  const __half2* g2 = (const __half2*)g;
  int e0 = row_start[d];
  int len = row_end[d] - e0;

  float2 a0 = __half22float2(g2[(size_t)d * 32 + sub]);  // self (dinv in g)
  float2 a1 = {0.f, 0.f}, a2 = {0.f, 0.f}, a3 = {0.f, 0.f};
  float2 a4 = {0.f, 0.f}, a5 = {0.f, 0.f}, a6 = {0.f, 0.f}, a7 = {0.f, 0.f};

  for (int i = 0; i < len; i += 8) {  // per-half-wave trip count (exec-mask divergence)
    int4 ca = *(const int4*)(col + e0 + i);
    int4 cb = *(const int4*)(col + e0 + i + 4);
    float2 h0 = __half22float2(g2[(size_t)ca.x * 32 + sub]);
    float2 h1 = __half22float2(g2[(size_t)ca.y * 32 + sub]);
    float2 h2 = __half22float2(g2[(size_t)ca.z * 32 + sub]);
    float2 h3 = __half22float2(g2[(size_t)ca.w * 32 + sub]);
    float2 h4 = __half22float2(g2[(size_t)cb.x * 32 + sub]);
    float2 h5 = __half22float2(g2[(size_t)cb.y * 32 + sub]);
    float2 h6 = __half22float2(g2[(size_t)cb.z * 32 + sub]);
    float2 h7 = __half22float2(g2[(size_t)cb.w * 32 + sub]);
    a0.x += h0.x; a0.y += h0.y; a1.x += h1.x; a1.y += h1.y;
    a2.x += h2.x; a2.y += h2.y; a3.x += h3.x; a3.y += h3.y;
    a4.x += h4.x; a4.y += h4.y; a5.x += h5.x; a5.y += h5.y;
    a6.x += h6.x; a6.y += h6.y; a7.x += h7.x; a7.y += h7.y;
  }
  float rx = ((a0.x + a1.x) + (a2.x + a3.x)) + ((a4.x + a5.x) + (a6.x + a7.x));
  float ry = ((a0.y + a1.y) + (a2.y + a3.y)) + ((a4.y + a5.y) + (a6.y + a7.y));
  float dv = dinv[d];
  float2 bv = ((const float2*)bias)[sub];
  float2 o;
  o.x = fmaf(rx, dv, bv.x);
  o.y = fmaf(ry, dv, bv.y);
  ((float2*)out)[(size_t)d * 32 + sub] = o;
}

// fp32 GEMM for the MLP: C[n,F] = op(A[n,64])@W[64,F] (+bias)(relu).
// Single-phase only (see R6/R8 spill rule).
template <int F>
__global__ __launch_bounds__(256) void gemm_kernel(const float* __restrict__ A, const float* __restrict__ W,
                                                   const float* __restrict__ bias, float* __restrict__ C,
                                                   int n, int reluIn, int reluOut) {
  constexpr int CPT = F / 8;
  __shared__ float Ws[64 * F];
  int t = threadIdx.x;
  for (int i = t; i < 64 * F / 4; i += 256) ((float4*)Ws)[i] = ((const float4*)W)[i];
  __syncthreads();

  int rg = t >> 3, cg = t & 7;
  int r0 = blockIdx.x * 128 + rg * 4;
  int c0 = cg * CPT;

  float acc[4][CPT];
#pragma unroll
  for (int i = 0; i < 4; i++)
#pragma unroll
    for (int j = 0; j < CPT; j++) acc[i][j] = 0.f;

  const float4* A4 = (const float4*)A;
  for (int kk = 0; kk < 16; kk++) {
    float4 a[4];
#pragma unroll
    for (int i = 0; i < 4; i++) {
      int r = r0 + i;
      float4 v = (r < n) ? A4[(size_t)r * 16 + kk] : make_float4(0.f, 0.f, 0.f, 0.f);
      if (reluIn) {
        v.x = fmaxf(v.x, 0.f); v.y = fmaxf(v.y, 0.f);
        v.z = fmaxf(v.z, 0.f); v.w = fmaxf(v.w, 0.f);
      }
      a[i] = v;
    }
#pragma unroll
    for (int q = 0; q < 4; q++) {
      int k = kk * 4 + q;
      float w[CPT];
      if constexpr (CPT % 4 == 0) {
#pragma unroll
        for (int j = 0; j < CPT / 4; j++)
          *(float4*)&w[4 * j] = *(const float4*)&Ws[k * F + c0 + 4 * j];  // ds_read_b128
      } else {
#pragma unroll
        for (int j = 0; j < CPT; j++) w[j] = Ws[k * F + c0 + j];
      }
#pragma unroll
      for (int i = 0; i < 4; i++) {
        float av = q == 0 ? a[i].x : q == 1 ? a[i].y : q == 2 ? a[i].z : a[i].w;
#pragma unroll
        for (int j = 0; j < CPT; j++) acc[i][j] = fmaf(av, w[j], acc[i][j]);
      }
    }
  }

  float bv[CPT];
#pragma unroll
  for (int j = 0; j < CPT; j++) bv[j] = bias ? bias[c0 + j] : 0.f;
#pragma unroll
  for (int i = 0; i < 4; i++) {
    int r = r0 + i;
    if (r < n) {
      float* crow = C + (size_t)r * F + c0;
#pragma unroll
      for (int j = 0; j < CPT; j++) {
        float v = acc[i][j] + bv[j];
        if (reluOut) v = fmaxf(v, 0.f);
        crow[j] = v;
      }
    }
  }
}

}  // namespace

extern "C" void kernel_launch(void* const* d_in, const int* in_sizes, int n_in,
                              void* d_out, int out_size, void* d_ws, size_t ws_size,
                              hipStream_t stream) {
  const float* x   = (const float*)d_in[0];
  const void*  ei  = d_in[1];
  const float* W1  = (const float*)d_in[2];
  const float* b1  = (const float*)d_in[3];
  const float* W2  = (const float*)d_in[4];
  const float* b2  = (const float*)d_in[5];
  const float* Wm1 = (const float*)d_in[6];
  const float* bm1 = (const float*)d_in[7];
  const float* Wm2 = (const float*)d_in[8];
  const float* bm2 = (const float*)d_in[9];
  float* out = (float*)d_out;

  char* ws = (char*)d_ws;
  size_t off = 0;
  auto alloc = [&](size_t bytes) -> void* {
    void* p = ws + off;
    off = (off + bytes + 511) & ~(size_t)511;
    return p;
  };
  int*      bucketCnt = (int*)     alloc((size_t)NBUCK * 4);
  unsigned* tmp       = (unsigned*)alloc((size_t)NBUCK * CAP * 4);  // 6.4 MB
  int*      colA      = (int*)     alloc((size_t)NBUCK * CAP * 4);  // 6.4 MB
  int*      rowS      = (int*)     alloc((size_t)N_NODES * 4);
  int*      rowE      = (int*)     alloc((size_t)N_NODES * 4);
  float*    dinv      = (float*)   alloc((size_t)N_NODES * 4);
  __half*   g1        = (__half*)  alloc((size_t)(N_NODES + 1) * 64 * 2);  // +1 zero row
  float*    hA        = (float*)   alloc((size_t)N_NODES * 64 * 4);
  float*    hB        = (float*)   alloc((size_t)N_NODES * 64 * 4);
  (void)ws_size; (void)in_sizes; (void)n_in; (void)out_size;

  dim3 b256(256);
  int gGemm = (N_NODES + 127) / 128;
  int gAgg  = N_NODES / 8;  // 12500, exact
  int gBkt  = (N_EDGES + EPB_A - 1) / EPB_A;

  // preprocessing: 2-pass bucket sort -> padded CSR (shared by both convs)
  hipMemsetAsync(bucketCnt, 0, (size_t)NBUCK * 4, stream);
  bucket_kernel<<<gBkt, b256, 0, stream>>>(ei, bucketCnt, tmp);
  csr_kernel<<<NBUCK, dim3(512), 0, stream>>>(tmp, bucketCnt, colA, rowS, rowE, dinv);

  // conv1: g1 = (x@W1)*dinv (fp16); hB = dinv*(self+SUM)+b1 (fp32)
  gemm_g_kernel<<<gGemm, b256, 0, stream>>>(x, W1, dinv, g1, 0);
  aggregate_kernel<<<gAgg, b256, 0, stream>>>(g1, colA, rowS, rowE, dinv, b1, hB);

  // conv2: g1 = (relu(hB)@W2)*dinv (fp16); hB = dinv*(self+SUM)+b2 (fp32)
  gemm_g_kernel<<<gGemm, b256, 0, stream>>>(hB, W2, dinv, g1, 1);
  aggregate_kernel<<<gAgg, b256, 0, stream>>>(g1, colA, rowS, rowE, dinv, b2, hB);

  // MLP: hA = relu(hB@Wm1+bm1); out = hA@Wm2+bm2  (two single-phase GEMMs)
  gemm_kernel<64><<<gGemm, b256, 0, stream>>>(hB, Wm1, bm1, hA, N_NODES, 0, 1);
  gemm_kernel<40><<<gGemm, b256, 0, stream>>>(hA, Wm2, bm2, out, N_NODES, 0, 0);
}